// Round 11
// baseline (478.895 us; speedup 1.0000x reference)
//
#include <hip/hip_runtime.h>
#include <hip/hip_bf16.h>
#include <cstdint>
#include <math.h>

// PathwayGraphEncoder: 3-layer GAT (+self-loops, scatter-softmax) -> mean pool
// -> VAE head with JAX partitionable-threefry eps.
// R11: agg4 went VALU-bound after fp8 (97% VALUBusy) => packed v_pk_fma_f32
// accumulation, __expf weights, 4 gathers in flight. fill/count: 4 edges per
// thread with hoisted loads + independent atomics (4x atomic MLP).

#define N_NODES 50000
#define N_EDGES 800000
#define NEG_SLOPE 0.2f

typedef __hip_bfloat16 bf16;
typedef short short8 __attribute__((ext_vector_type(8)));
typedef float floatx4 __attribute__((ext_vector_type(4)));
typedef float floatx2 __attribute__((ext_vector_type(2)));

__device__ __forceinline__ float bf2f(bf16 v){ return __bfloat162float(v); }
__device__ __forceinline__ float bflo(unsigned u){ union{unsigned u; float f;} c; c.u = u<<16; return c.f; }
__device__ __forceinline__ float bfhi(unsigned u){ union{unsigned u; float f;} c; c.u = u & 0xFFFF0000u; return c.f; }
__device__ __forceinline__ float leaky(float v){ return v>0.f ? v : NEG_SLOPE*v; }
__device__ __forceinline__ unsigned short f2bu(float f){
  union{ bf16 b; unsigned short u; } c; c.b = __float2bfloat16(f); return c.u;
}
__device__ __forceinline__ unsigned char f2fp8(float v){
  int p = __builtin_amdgcn_cvt_pk_fp8_f32(v, v, 0, false);
  return (unsigned char)(p & 0xff);
}
// 16 fp8 -> 8 packed float2 FMAs into acc2[0..3] (v_pk_fma_f32 path)
__device__ __forceinline__ void acc8_pk(floatx2* a, uint4 hv, float w){
  floatx2 w2; w2[0]=w; w2[1]=w;
  a[0] += __builtin_amdgcn_cvt_pk_f32_fp8((int)hv.x, false) * w2;
  a[1] += __builtin_amdgcn_cvt_pk_f32_fp8((int)hv.x, true ) * w2;
  a[2] += __builtin_amdgcn_cvt_pk_f32_fp8((int)hv.y, false) * w2;
  a[3] += __builtin_amdgcn_cvt_pk_f32_fp8((int)hv.y, true ) * w2;
  a[4] += __builtin_amdgcn_cvt_pk_f32_fp8((int)hv.z, false) * w2;
  a[5] += __builtin_amdgcn_cvt_pk_f32_fp8((int)hv.z, true ) * w2;
  a[6] += __builtin_amdgcn_cvt_pk_f32_fp8((int)hv.w, false) * w2;
  a[7] += __builtin_amdgcn_cvt_pk_f32_fp8((int)hv.w, true ) * w2;
}

// ---------------- threefry2x32 (JAX-compatible) ----------------
__device__ __forceinline__ void tf_round(unsigned& x0, unsigned& x1, int r){
  x0 += x1; x1 = (x1<<r)|(x1>>(32-r)); x1 ^= x0;
}
__device__ __forceinline__ void threefry2x32(unsigned k0, unsigned k1, unsigned& x0, unsigned& x1){
  unsigned ks2 = k0 ^ k1 ^ 0x1BD11BDAu;
  x0 += k0; x1 += k1;
  tf_round(x0,x1,13); tf_round(x0,x1,15); tf_round(x0,x1,26); tf_round(x0,x1,6);
  x0 += k1; x1 += ks2 + 1u;
  tf_round(x0,x1,17); tf_round(x0,x1,29); tf_round(x0,x1,16); tf_round(x0,x1,24);
  x0 += ks2; x1 += k0 + 2u;
  tf_round(x0,x1,13); tf_round(x0,x1,15); tf_round(x0,x1,26); tf_round(x0,x1,6);
  x0 += k0; x1 += k1 + 3u;
  tf_round(x0,x1,17); tf_round(x0,x1,29); tf_round(x0,x1,16); tf_round(x0,x1,24);
  x0 += k1; x1 += ks2 + 4u;
  tf_round(x0,x1,13); tf_round(x0,x1,15); tf_round(x0,x1,26); tf_round(x0,x1,6);
  x0 += ks2; x1 += k0 + 5u;
}

// Giles single-precision erfinv (XLA ErfInv32 coefficients)
__device__ __forceinline__ float erfinv_approx(float x){
  float w = -log1pf(-x*x);
  float p;
  if (w < 5.0f){
    w = w - 2.5f;
    p = 2.81022636e-08f;
    p = fmaf(p,w,3.43273939e-07f);
    p = fmaf(p,w,-3.5233877e-06f);
    p = fmaf(p,w,-4.39150654e-06f);
    p = fmaf(p,w,0.00021858087f);
    p = fmaf(p,w,-0.00125372503f);
    p = fmaf(p,w,-0.00417768164f);
    p = fmaf(p,w,0.246640727f);
    p = fmaf(p,w,1.50140941f);
  } else {
    w = sqrtf(w) - 3.0f;
    p = -0.000200214257f;
    p = fmaf(p,w,0.000100950558f);
    p = fmaf(p,w,0.00134934322f);
    p = fmaf(p,w,-0.00367342844f);
    p = fmaf(p,w,0.00573950773f);
    p = fmaf(p,w,-0.0076224613f);
    p = fmaf(p,w,0.00943887047f);
    p = fmaf(p,w,1.00167406f);
    p = fmaf(p,w,2.83297682f);
  }
  return p*x;
}

// ------- W transposes (all 3 in one launch): Wt[n][k] bf16 from W[k][n] f32 -------
__global__ __launch_bounds__(256) void wt_all_kernel(
        const float* __restrict__ W1, const float* __restrict__ W2,
        const float* __restrict__ W3, short* __restrict__ Wt1,
        short* __restrict__ Wt2, short* __restrict__ Wt3){
  const float* W; short* Wt; int Nn;
  if (blockIdx.z == 0){ W = W1; Wt = Wt1; Nn = 256; }
  else if (blockIdx.z == 1){ W = W2; Wt = Wt2; Nn = 256; }
  else { W = W3; Wt = Wt3; Nn = 64; }
  const int n0 = blockIdx.x*32, k0 = blockIdx.y*32;
  if (n0 >= Nn) return;
  __shared__ float tile[32][33];
  const int tx = threadIdx.x & 31, ty = threadIdx.x >> 5;   // 32 x 8
  #pragma unroll
  for (int i=0;i<4;++i)
    tile[ty+8*i][tx] = W[(size_t)(k0+ty+8*i)*Nn + n0 + tx];
  __syncthreads();
  #pragma unroll
  for (int i=0;i<4;++i)
    Wt[(size_t)(n0+ty+8*i)*256 + k0 + tx] = (short)f2bu(tile[tx][ty+8*i]);
}

// ---------------- MFMA GEMM + fused attention coefficients ----------------
// OUT=256: out is fp8 e4m3 (gather payload). OUT=64: out is bf16.
template<int OUT, bool INBF>
__global__ __launch_bounds__(256) void gemm_mfma_kernel(const void* __restrict__ inp,
        const short* __restrict__ Wt, void* __restrict__ outv,
        const float* __restrict__ a_s, const float* __restrict__ a_d,
        float* __restrict__ als, float* __restrict__ ald, int N){
  constexpr int M_BLK = (OUT==256) ? 64 : 256;
  constexpr int H = (OUT==256) ? 4 : 1;
  __shared__ short As[M_BLK*48];
  __shared__ short Bs[OUT*48];
  const int t = threadIdx.x;
  const int w = t>>6, lane = t&63;
  const int lm = lane&15, g = lane>>4;
  const int m0 = blockIdx.x * M_BLK;
  const int m_off = (OUT==256) ? 0 : w*64;
  const int n0    = (OUT==256) ? w*64 : 0;

  floatx4 acc[4][4] = {};

  for (int kk=0; kk<8; ++kk){
    const int k0 = kk*32;
    __syncthreads();
    for (int a = t; a < M_BLK*4; a += 256){
      int r = a>>2, c = a&3;
      int gr = m0 + r;
      uint4 v = make_uint4(0u,0u,0u,0u);
      if (gr < N){
        if constexpr (INBF){
          v = *(const uint4*)((const bf16*)inp + (size_t)gr*256 + k0 + c*8);
        } else {
          const float* p = (const float*)inp + (size_t)gr*256 + k0 + c*8;
          float4 f0 = *(const float4*)p;
          float4 f1 = *(const float4*)(p+4);
          v.x = (unsigned)f2bu(f0.x) | ((unsigned)f2bu(f0.y)<<16);
          v.y = (unsigned)f2bu(f0.z) | ((unsigned)f2bu(f0.w)<<16);
          v.z = (unsigned)f2bu(f1.x) | ((unsigned)f2bu(f1.y)<<16);
          v.w = (unsigned)f2bu(f1.z) | ((unsigned)f2bu(f1.w)<<16);
        }
      }
      *(uint4*)&As[r*48 + c*8] = v;
    }
    for (int a = t; a < OUT*4; a += 256){
      int r = a>>2, c = a&3;
      uint4 v = *(const uint4*)(Wt + (size_t)r*256 + k0 + c*8);
      *(uint4*)&Bs[r*48 + c*8] = v;
    }
    __syncthreads();
    short8 af[4], bfr[4];
    #pragma unroll
    for (int mt=0;mt<4;++mt)
      af[mt] = *(const short8*)&As[(m_off + mt*16 + lm)*48 + g*8];
    #pragma unroll
    for (int nt=0;nt<4;++nt)
      bfr[nt] = *(const short8*)&Bs[(n0 + nt*16 + lm)*48 + g*8];
    #pragma unroll
    for (int mt=0;mt<4;++mt)
      #pragma unroll
      for (int nt=0;nt<4;++nt)
        acc[mt][nt] = __builtin_amdgcn_mfma_f32_16x16x32_bf16(af[mt], bfr[nt], acc[mt][nt], 0, 0, 0);
  }

  float asv[4], adv[4];
  #pragma unroll
  for (int nt=0;nt<4;++nt){
    asv[nt] = a_s[n0 + nt*16 + lm];
    adv[nt] = a_d[n0 + nt*16 + lm];
  }
  const int head = (OUT==256) ? w : 0;
  #pragma unroll
  for (int mt=0;mt<4;++mt){
    #pragma unroll
    for (int reg=0;reg<4;++reg){
      int gr = m0 + m_off + mt*16 + g*4 + reg;
      bool valid = gr < N;
      float ps = 0.f, pd = 0.f;
      #pragma unroll
      for (int nt=0;nt<4;++nt){
        float v = acc[mt][nt][reg];
        if (valid){
          if constexpr (OUT==256){
            ((unsigned char*)outv)[(size_t)gr*256 + n0 + nt*16 + lm] = f2fp8(v);
          } else {
            ((bf16*)outv)[(size_t)gr*OUT + n0 + nt*16 + lm] = __float2bfloat16(v);
          }
        }
        ps = fmaf(v, asv[nt], ps);
        pd = fmaf(v, adv[nt], pd);
      }
      #pragma unroll
      for (int o=1;o<16;o<<=1){ ps += __shfl_xor(ps,o); pd += __shfl_xor(pd,o); }
      if (lm==0 && valid){
        als[gr*H + head] = ps;
        ald[gr*H + head] = pd;
      }
    }
  }
}

// ---------------- scan-free CSR build (by destination, + self-loops) ----------------
__global__ void count_kernel(const int* __restrict__ ei, int* __restrict__ deg,
        int E, int stride){
  int tid = blockIdx.x*blockDim.x+threadIdx.x;
  int d[4]; bool v[4];
  #pragma unroll
  for (int j=0;j<4;++j){
    int e = tid + j*stride;
    v[j] = e < E;
    d[j] = v[j] ? ei[E+e] : 0;
  }
  #pragma unroll
  for (int j=0;j<4;++j) if (v[j]) atomicAdd(&deg[d[j]], 1);
}
__global__ void assign_kernel(const int* __restrict__ deg, int* __restrict__ off,
        int* __restrict__ cursor, int* __restrict__ total, int N){
  int i = blockIdx.x*blockDim.x+threadIdx.x;
  if (i<N){
    int d = deg[i] + 1;                       // +1 self-loop
    int start = atomicAdd(total, d);          // unordered segments: fine
    off[i] = start; cursor[i] = start;
  }
}
__global__ void fill_kernel(const int* __restrict__ ei, int* __restrict__ cursor,
        int* __restrict__ csr_src, int E, int N, int stride){
  int tid = blockIdx.x*blockDim.x+threadIdx.x;
  const int ET = E + N;
  int s[4], d[4]; bool v[4];
  #pragma unroll
  for (int j=0;j<4;++j){
    int e = tid + j*stride;
    v[j] = e < ET;
    if (v[j]){
      s[j] = (e < E) ? ei[e]   : e-E;
      d[j] = (e < E) ? ei[E+e] : e-E;
    }
  }
  int p[4];
  #pragma unroll
  for (int j=0;j<4;++j) if (v[j]) p[j] = atomicAdd(&cursor[d[j]], 1);
  #pragma unroll
  for (int j=0;j<4;++j) if (v[j]) csr_src[p[j]] = s[j];
}

// ------- single-pass scatter-softmax + aggregate, H=4, fp8 h (1 wave/node) -------
// lane = parity r (lane>>4, 4 edges) x feature-16 f (lane&15); uint4 = 16 fp8
// => 4 rows per wave-instruction, 4 loads in flight (step 16); packed f32 FMAs.
template<bool ELU>
__global__ __launch_bounds__(64) void aggregate4_kernel(const unsigned char* __restrict__ h8,
        const float* __restrict__ als, const float* __restrict__ ald,
        const int* __restrict__ off, const int* __restrict__ deg,
        const int* __restrict__ csr_src,
        const float* __restrict__ bias, bf16* __restrict__ out){
  __shared__ int   s_src[64];
  __shared__ float s_w[64][4];
  const int n = blockIdx.x, lane = threadIdx.x;
  const int r = lane>>4;            // edge parity (0..3)
  const int f = lane&15;            // features f*16..f*16+15
  const int head = f>>2;
  const int p0 = off[n], cnt = deg[n]+1;
  const float4 aldn4 = *(const float4*)(ald + n*4);
  float ssum = 0.f;
  floatx2 acc2[8] = {};
  for (int c=0; c<cnt; c+=64){
    int e = c + lane;
    int src = n; float4 w4 = make_float4(0.f,0.f,0.f,0.f);
    if (e < cnt){
      src = csr_src[p0+e];
      float4 av = *(const float4*)(als + src*4);
      w4.x = __expf(leaky(av.x + aldn4.x));
      w4.y = __expf(leaky(av.y + aldn4.y));
      w4.z = __expf(leaky(av.z + aldn4.z));
      w4.w = __expf(leaky(av.w + aldn4.w));
    }
    s_src[lane] = src;                 // pad: src=n (valid addr), w=0
    *(float4*)&s_w[lane][0] = w4;
    int ce = min(64, cnt - c);
    int cp = (ce+15)&~15;              // step 16: 4 uint4 loads in flight
    for (int i=0;i<cp;i+=16){
      int src0 = s_src[i+r],   src1 = s_src[i+4+r];
      int src2 = s_src[i+8+r], src3 = s_src[i+12+r];
      float w0 = s_w[i+r][head],   w1 = s_w[i+4+r][head];
      float w2 = s_w[i+8+r][head], w3 = s_w[i+12+r][head];
      uint4 h0 = *(const uint4*)(h8 + (size_t)src0*256 + f*16);
      uint4 h1 = *(const uint4*)(h8 + (size_t)src1*256 + f*16);
      uint4 h2 = *(const uint4*)(h8 + (size_t)src2*256 + f*16);
      uint4 h3 = *(const uint4*)(h8 + (size_t)src3*256 + f*16);
      ssum += (w0 + w1) + (w2 + w3);
      acc8_pk(acc2, h0, w0);
      acc8_pk(acc2, h1, w1);
      acc8_pk(acc2, h2, w2);
      acc8_pk(acc2, h3, w3);
    }
  }
  float acc[16];
  #pragma unroll
  for (int j=0;j<8;++j){ acc[2*j]=acc2[j][0]; acc[2*j+1]=acc2[j][1]; }
  #pragma unroll
  for (int j=0;j<16;++j){
    acc[j] += __shfl_xor(acc[j], 16);
    acc[j] += __shfl_xor(acc[j], 32);
  }
  ssum += __shfl_xor(ssum, 16);
  ssum += __shfl_xor(ssum, 32);
  if (r==0){
    float inv = 1.f/(ssum + 1e-16f);
    #pragma unroll
    for (int half=0; half<2; ++half){
      float4 b0 = *(const float4*)(bias + f*16 + half*8);
      float4 b1 = *(const float4*)(bias + f*16 + half*8 + 4);
      float rv[8];
      rv[0]=acc[half*8+0]*inv+b0.x; rv[1]=acc[half*8+1]*inv+b0.y;
      rv[2]=acc[half*8+2]*inv+b0.z; rv[3]=acc[half*8+3]*inv+b0.w;
      rv[4]=acc[half*8+4]*inv+b1.x; rv[5]=acc[half*8+5]*inv+b1.y;
      rv[6]=acc[half*8+6]*inv+b1.z; rv[7]=acc[half*8+7]*inv+b1.w;
      union{ bf16 b[8]; uint4 u; } pk;
      #pragma unroll
      for (int j=0;j<8;++j){
        float v = rv[j];
        if (ELU) v = (v>0.f)?v:expm1f(v);
        pk.b[j] = __float2bfloat16(v);
      }
      *(uint4*)(out + (size_t)n*256 + f*16 + half*8) = pk.u;
    }
  }
}

// ------- single-pass scatter-softmax + aggregate, H=1, bf16 h (1 wave/node) -------
__global__ __launch_bounds__(64) void aggregate1_kernel(const bf16* __restrict__ h,
        const float* __restrict__ als, const float* __restrict__ ald,
        const int* __restrict__ off, const int* __restrict__ deg,
        const int* __restrict__ csr_src,
        const float* __restrict__ bias, bf16* __restrict__ out){
  __shared__ int   s_src[64];
  __shared__ float s_w[64];
  const int n = blockIdx.x, lane = threadIdx.x;
  const int r = lane>>4;            // edge parity (0..3)
  const int f = lane&15;            // feature quad: features f*4..f*4+3
  const int p0 = off[n], cnt = deg[n]+1;
  const float aldn = ald[n];
  float ssum = 0.f;
  float acc[4] = {};
  for (int c=0; c<cnt; c+=64){
    int e = c + lane;
    int src = n; float wv = 0.f;
    if (e < cnt){
      src = csr_src[p0+e];
      wv = __expf(leaky(als[src] + aldn));
    }
    s_src[lane] = src; s_w[lane] = wv;
    int ce = min(64, cnt - c);
    int cp = (ce+15)&~15;            // step 16: 4 uint2 loads in flight
    for (int i=0;i<cp;i+=16){
      int src0 = s_src[i+r],   src1 = s_src[i+4+r];
      int src2 = s_src[i+8+r], src3 = s_src[i+12+r];
      float w0 = s_w[i+r],   w1 = s_w[i+4+r];
      float w2 = s_w[i+8+r], w3 = s_w[i+12+r];
      uint2 h0 = *(const uint2*)(h + (size_t)src0*64 + f*4);
      uint2 h1 = *(const uint2*)(h + (size_t)src1*64 + f*4);
      uint2 h2 = *(const uint2*)(h + (size_t)src2*64 + f*4);
      uint2 h3 = *(const uint2*)(h + (size_t)src3*64 + f*4);
      ssum += (w0 + w1) + (w2 + w3);
      acc[0]=fmaf(bflo(h0.x),w0,acc[0]); acc[1]=fmaf(bfhi(h0.x),w0,acc[1]);
      acc[2]=fmaf(bflo(h0.y),w0,acc[2]); acc[3]=fmaf(bfhi(h0.y),w0,acc[3]);
      acc[0]=fmaf(bflo(h1.x),w1,acc[0]); acc[1]=fmaf(bfhi(h1.x),w1,acc[1]);
      acc[2]=fmaf(bflo(h1.y),w1,acc[2]); acc[3]=fmaf(bfhi(h1.y),w1,acc[3]);
      acc[0]=fmaf(bflo(h2.x),w2,acc[0]); acc[1]=fmaf(bfhi(h2.x),w2,acc[1]);
      acc[2]=fmaf(bflo(h2.y),w2,acc[2]); acc[3]=fmaf(bfhi(h2.y),w2,acc[3]);
      acc[0]=fmaf(bflo(h3.x),w3,acc[0]); acc[1]=fmaf(bfhi(h3.x),w3,acc[1]);
      acc[2]=fmaf(bflo(h3.y),w3,acc[2]); acc[3]=fmaf(bfhi(h3.y),w3,acc[3]);
    }
  }
  #pragma unroll
  for (int j=0;j<4;++j){
    acc[j] += __shfl_xor(acc[j], 16);
    acc[j] += __shfl_xor(acc[j], 32);
  }
  ssum += __shfl_xor(ssum, 16);
  ssum += __shfl_xor(ssum, 32);
  if (r==0){
    float inv = 1.f/(ssum + 1e-16f);
    union{ bf16 b[4]; uint2 u; } pk;
    #pragma unroll
    for (int j=0;j<4;++j) pk.b[j] = __float2bfloat16(acc[j]*inv + bias[f*4+j]);
    *(uint2*)(out + (size_t)n*64 + f*4) = pk.u;
  }
}

// ---------------- chunked pooling (batch sorted) ----------------
__global__ __launch_bounds__(64) void pool_kernel(const bf16* __restrict__ h3,
        const int* __restrict__ batch, float* __restrict__ psum, float* __restrict__ pcnt,
        int N, int chunk){
  int n0 = blockIdx.x*chunk;
  if (n0 >= N) return;
  int n1 = min(N, n0+chunk);
  int t = threadIdx.x;
  int gcur = batch[n0];
  float acc = 0.f, cnt = 0.f;
  for (int n=n0; n<n1; ++n){
    int g = batch[n];
    if (g != gcur){
      atomicAdd(&psum[gcur*64+t], acc);
      if (t==0) atomicAdd(&pcnt[gcur], cnt);
      acc = 0.f; cnt = 0.f; gcur = g;
    }
    acc += bf2f(h3[(size_t)n*64+t]);
    cnt += 1.f;
  }
  atomicAdd(&psum[gcur*64+t], acc);
  if (t==0) atomicAdd(&pcnt[gcur], cnt);
}

__global__ __launch_bounds__(64) void head_kernel(const float* __restrict__ psum,
        const float* __restrict__ pcnt,
        const float* __restrict__ Wmu, const float* __restrict__ bmu,
        const float* __restrict__ Wlv, const float* __restrict__ blv,
        float* __restrict__ out){
  int g = blockIdx.x, t = threadIdx.x;
  __shared__ float p[64];
  float cnt = fmaxf(pcnt[g], 1.0f);
  p[t] = psum[g*64+t] / cnt;
  __syncthreads();
  float mu = bmu[t], lv = blv[t];
  for (int k=0;k<64;++k){
    float pk = p[k];
    mu = fmaf(pk, Wmu[(size_t)k*64+t], mu);
    lv = fmaf(pk, Wlv[(size_t)k*64+t], lv);
  }
  int i = g*64 + t;
  unsigned x0 = 0u, x1 = (unsigned)i;
  threefry2x32(0u, 42u, x0, x1);
  unsigned bits = x0 ^ x1;
  float f = __uint_as_float((bits>>9) | 0x3F800000u) - 1.0f;   // [0,1)
  const float lo = __uint_as_float(0xBF7FFFFFu);               // -(1-2^-24)
  float u = fmaxf(lo, f*2.0f + lo);
  float eps = 1.41421356f * erfinv_approx(u);
  float z = mu + eps * expf(0.5f*lv);
  out[i]        = mu;
  out[4096 + i] = lv;
  out[8192 + i] = z;
}

// ---------------- launch ----------------
extern "C" void kernel_launch(void* const* d_in, const int* in_sizes, int n_in,
                              void* d_out, int out_size, void* d_ws, size_t ws_size,
                              hipStream_t stream){
  const float* x    = (const float*)d_in[0];
  const int*   ei   = (const int*)d_in[1];
  const int*   batch= (const int*)d_in[2];
  const float* W1   = (const float*)d_in[3];
  const float* a1s  = (const float*)d_in[4];
  const float* a1d  = (const float*)d_in[5];
  const float* b1   = (const float*)d_in[6];
  const float* W2   = (const float*)d_in[7];
  const float* a2s  = (const float*)d_in[8];
  const float* a2d  = (const float*)d_in[9];
  const float* b2   = (const float*)d_in[10];
  const float* W3   = (const float*)d_in[11];
  const float* a3s  = (const float*)d_in[12];
  const float* a3d  = (const float*)d_in[13];
  const float* b3   = (const float*)d_in[14];
  const float* Wmu  = (const float*)d_in[15];
  const float* bmu  = (const float*)d_in[16];
  const float* Wlv  = (const float*)d_in[17];
  const float* blv  = (const float*)d_in[18];
  float* out = (float*)d_out;

  const int N = N_NODES, E = N_EDGES;
  const int ET = E + N;

  char* ws = (char*)d_ws;
  size_t o = 0;
  auto alloc = [&](size_t bytes)->void*{
    void* p = ws + o; o += (bytes + 255) & ~(size_t)255; return p;
  };
  bf16*  hA      = (bf16*) alloc((size_t)N*256*2);       // 25.6 MB (agg out / gemm in)
  unsigned char* hB8 = (unsigned char*)alloc((size_t)N*256); // 12.8 MB fp8 gather payload
  bf16*  h3      = (bf16*) alloc((size_t)N*64*2);        // 6.4 MB (layer3 gemm out)
  float* als     = (float*)alloc((size_t)N*4*4);
  float* ald     = (float*)alloc((size_t)N*4*4);
  int*   deg     = (int*)  alloc((size_t)(N+1)*4);       // deg[N] = total
  int*   total   = deg + N;
  int*   off     = (int*)  alloc((size_t)N*4);
  int*   cursor  = (int*)  alloc((size_t)N*4);
  int*   csr_src = (int*)  alloc((size_t)ET*4);
  short* Wt1     = (short*)alloc(256*256*2);
  short* Wt2     = (short*)alloc(256*256*2);
  short* Wt3     = (short*)alloc(64*256*2);
  float* psum    = (float*)alloc(64*64*4 + 64*4);        // psum + pcnt contiguous
  float* pcnt    = psum + 64*64;
  (void)ws_size; (void)n_in; (void)in_sizes; (void)out_size;

  const int TB = 256;

  // W transposes (bf16 [n][k]) — single launch
  wt_all_kernel<<<dim3(8,8,3), 256, 0, stream>>>(W1, W2, W3, Wt1, Wt2, Wt3);

  // scan-free CSR by destination (rebuilt every call; ws re-poisoned per launch)
  hipMemsetAsync(deg, 0, (size_t)(N+1)*4, stream);
  {
    int cthreads = (E + 3)/4;
    int cgrid = (cthreads + TB - 1)/TB;
    count_kernel<<<cgrid, TB, 0, stream>>>(ei, deg, E, cgrid*TB);
  }
  assign_kernel<<<(N+TB-1)/TB, TB, 0, stream>>>(deg, off, cursor, total, N);
  {
    int fthreads = (ET + 3)/4;
    int fgrid = (fthreads + TB - 1)/TB;
    fill_kernel<<<fgrid, TB, 0, stream>>>(ei, cursor, csr_src, E, N, fgrid*TB);
  }

  // ---- layer 1: x(f32) @ W1, H=4, ELU ----
  gemm_mfma_kernel<256,false><<<(N+63)/64, 256, 0, stream>>>(x, Wt1, hB8, a1s, a1d, als, ald, N);
  aggregate4_kernel<true><<<N, 64, 0, stream>>>(hB8, als, ald, off, deg, csr_src, b1, hA);

  // ---- layer 2: hA(bf16) @ W2, H=4, ELU ----
  gemm_mfma_kernel<256,true><<<(N+63)/64, 256, 0, stream>>>(hA, Wt2, hB8, a2s, a2d, als, ald, N);
  aggregate4_kernel<true><<<N, 64, 0, stream>>>(hB8, als, ald, off, deg, csr_src, b2, hA);

  // ---- layer 3: hA(bf16) @ W3, H=1, no ELU ----
  gemm_mfma_kernel<64,true><<<(N+255)/256, 256, 0, stream>>>(hA, Wt3, h3, a3s, a3d, als, ald, N);
  aggregate1_kernel<<<N, 64, 0, stream>>>(h3, als, ald, off, deg, csr_src, b3, hA);

  // ---- pool + VAE head ----
  hipMemsetAsync(psum, 0, 64*64*4 + 64*4, stream);
  const int PBLK = 512;
  const int chunk = (N + PBLK - 1)/PBLK;
  pool_kernel<<<PBLK, 64, 0, stream>>>(hA, batch, psum, pcnt, N, chunk);
  head_kernel<<<64, 64, 0, stream>>>(psum, pcnt, Wmu, bmu, Wlv, blv, out);
}

// Round 12
// 466.475 us; speedup vs baseline: 1.0266x; 1.0266x over previous
//
#include <hip/hip_runtime.h>
#include <hip/hip_bf16.h>
#include <cstdint>
#include <math.h>

// PathwayGraphEncoder: 3-layer GAT (+self-loops, scatter-softmax) -> mean pool
// -> VAE head with JAX partitionable-threefry eps.
// R12: revert R11's register-heavy agg loops (44 VGPR -> 47% occ regression);
// back to R10 scalar-fma step-8 shape (28 VGPR) + __expf, and 2 nodes/block
// (128 thr, 2 independent waves, per-wave LDS) to raise wave supply.
// Keep R11's 4-way count/fill (it removed fill from top-5).

#define N_NODES 50000
#define N_EDGES 800000
#define NEG_SLOPE 0.2f

typedef __hip_bfloat16 bf16;
typedef short short8 __attribute__((ext_vector_type(8)));
typedef float floatx4 __attribute__((ext_vector_type(4)));
typedef float floatx2 __attribute__((ext_vector_type(2)));

__device__ __forceinline__ float bf2f(bf16 v){ return __bfloat162float(v); }
__device__ __forceinline__ float bflo(unsigned u){ union{unsigned u; float f;} c; c.u = u<<16; return c.f; }
__device__ __forceinline__ float bfhi(unsigned u){ union{unsigned u; float f;} c; c.u = u & 0xFFFF0000u; return c.f; }
__device__ __forceinline__ float leaky(float v){ return v>0.f ? v : NEG_SLOPE*v; }
__device__ __forceinline__ unsigned short f2bu(float f){
  union{ bf16 b; unsigned short u; } c; c.b = __float2bfloat16(f); return c.u;
}
__device__ __forceinline__ unsigned char f2fp8(float v){
  int p = __builtin_amdgcn_cvt_pk_fp8_f32(v, v, 0, false);
  return (unsigned char)(p & 0xff);
}
__device__ __forceinline__ void acc_fp8x4(float* acc, unsigned wrd, float wgt){
  floatx2 lo = __builtin_amdgcn_cvt_pk_f32_fp8((int)wrd, false);
  floatx2 hi = __builtin_amdgcn_cvt_pk_f32_fp8((int)wrd, true);
  acc[0] = fmaf(lo[0], wgt, acc[0]);
  acc[1] = fmaf(lo[1], wgt, acc[1]);
  acc[2] = fmaf(hi[0], wgt, acc[2]);
  acc[3] = fmaf(hi[1], wgt, acc[3]);
}

// ---------------- threefry2x32 (JAX-compatible) ----------------
__device__ __forceinline__ void tf_round(unsigned& x0, unsigned& x1, int r){
  x0 += x1; x1 = (x1<<r)|(x1>>(32-r)); x1 ^= x0;
}
__device__ __forceinline__ void threefry2x32(unsigned k0, unsigned k1, unsigned& x0, unsigned& x1){
  unsigned ks2 = k0 ^ k1 ^ 0x1BD11BDAu;
  x0 += k0; x1 += k1;
  tf_round(x0,x1,13); tf_round(x0,x1,15); tf_round(x0,x1,26); tf_round(x0,x1,6);
  x0 += k1; x1 += ks2 + 1u;
  tf_round(x0,x1,17); tf_round(x0,x1,29); tf_round(x0,x1,16); tf_round(x0,x1,24);
  x0 += ks2; x1 += k0 + 2u;
  tf_round(x0,x1,13); tf_round(x0,x1,15); tf_round(x0,x1,26); tf_round(x0,x1,6);
  x0 += k0; x1 += k1 + 3u;
  tf_round(x0,x1,17); tf_round(x0,x1,29); tf_round(x0,x1,16); tf_round(x0,x1,24);
  x0 += k1; x1 += ks2 + 4u;
  tf_round(x0,x1,13); tf_round(x0,x1,15); tf_round(x0,x1,26); tf_round(x0,x1,6);
  x0 += ks2; x1 += k0 + 5u;
}

// Giles single-precision erfinv (XLA ErfInv32 coefficients)
__device__ __forceinline__ float erfinv_approx(float x){
  float w = -log1pf(-x*x);
  float p;
  if (w < 5.0f){
    w = w - 2.5f;
    p = 2.81022636e-08f;
    p = fmaf(p,w,3.43273939e-07f);
    p = fmaf(p,w,-3.5233877e-06f);
    p = fmaf(p,w,-4.39150654e-06f);
    p = fmaf(p,w,0.00021858087f);
    p = fmaf(p,w,-0.00125372503f);
    p = fmaf(p,w,-0.00417768164f);
    p = fmaf(p,w,0.246640727f);
    p = fmaf(p,w,1.50140941f);
  } else {
    w = sqrtf(w) - 3.0f;
    p = -0.000200214257f;
    p = fmaf(p,w,0.000100950558f);
    p = fmaf(p,w,0.00134934322f);
    p = fmaf(p,w,-0.00367342844f);
    p = fmaf(p,w,0.00573950773f);
    p = fmaf(p,w,-0.0076224613f);
    p = fmaf(p,w,0.00943887047f);
    p = fmaf(p,w,1.00167406f);
    p = fmaf(p,w,2.83297682f);
  }
  return p*x;
}

// ------- W transposes (all 3 in one launch): Wt[n][k] bf16 from W[k][n] f32 -------
__global__ __launch_bounds__(256) void wt_all_kernel(
        const float* __restrict__ W1, const float* __restrict__ W2,
        const float* __restrict__ W3, short* __restrict__ Wt1,
        short* __restrict__ Wt2, short* __restrict__ Wt3){
  const float* W; short* Wt; int Nn;
  if (blockIdx.z == 0){ W = W1; Wt = Wt1; Nn = 256; }
  else if (blockIdx.z == 1){ W = W2; Wt = Wt2; Nn = 256; }
  else { W = W3; Wt = Wt3; Nn = 64; }
  const int n0 = blockIdx.x*32, k0 = blockIdx.y*32;
  if (n0 >= Nn) return;
  __shared__ float tile[32][33];
  const int tx = threadIdx.x & 31, ty = threadIdx.x >> 5;   // 32 x 8
  #pragma unroll
  for (int i=0;i<4;++i)
    tile[ty+8*i][tx] = W[(size_t)(k0+ty+8*i)*Nn + n0 + tx];
  __syncthreads();
  #pragma unroll
  for (int i=0;i<4;++i)
    Wt[(size_t)(n0+ty+8*i)*256 + k0 + tx] = (short)f2bu(tile[tx][ty+8*i]);
}

// ---------------- MFMA GEMM + fused attention coefficients ----------------
// OUT=256: out is fp8 e4m3 (gather payload). OUT=64: out is bf16.
template<int OUT, bool INBF>
__global__ __launch_bounds__(256) void gemm_mfma_kernel(const void* __restrict__ inp,
        const short* __restrict__ Wt, void* __restrict__ outv,
        const float* __restrict__ a_s, const float* __restrict__ a_d,
        float* __restrict__ als, float* __restrict__ ald, int N){
  constexpr int M_BLK = (OUT==256) ? 64 : 256;
  constexpr int H = (OUT==256) ? 4 : 1;
  __shared__ short As[M_BLK*48];
  __shared__ short Bs[OUT*48];
  const int t = threadIdx.x;
  const int w = t>>6, lane = t&63;
  const int lm = lane&15, g = lane>>4;
  const int m0 = blockIdx.x * M_BLK;
  const int m_off = (OUT==256) ? 0 : w*64;
  const int n0    = (OUT==256) ? w*64 : 0;

  floatx4 acc[4][4] = {};

  for (int kk=0; kk<8; ++kk){
    const int k0 = kk*32;
    __syncthreads();
    for (int a = t; a < M_BLK*4; a += 256){
      int r = a>>2, c = a&3;
      int gr = m0 + r;
      uint4 v = make_uint4(0u,0u,0u,0u);
      if (gr < N){
        if constexpr (INBF){
          v = *(const uint4*)((const bf16*)inp + (size_t)gr*256 + k0 + c*8);
        } else {
          const float* p = (const float*)inp + (size_t)gr*256 + k0 + c*8;
          float4 f0 = *(const float4*)p;
          float4 f1 = *(const float4*)(p+4);
          v.x = (unsigned)f2bu(f0.x) | ((unsigned)f2bu(f0.y)<<16);
          v.y = (unsigned)f2bu(f0.z) | ((unsigned)f2bu(f0.w)<<16);
          v.z = (unsigned)f2bu(f1.x) | ((unsigned)f2bu(f1.y)<<16);
          v.w = (unsigned)f2bu(f1.z) | ((unsigned)f2bu(f1.w)<<16);
        }
      }
      *(uint4*)&As[r*48 + c*8] = v;
    }
    for (int a = t; a < OUT*4; a += 256){
      int r = a>>2, c = a&3;
      uint4 v = *(const uint4*)(Wt + (size_t)r*256 + k0 + c*8);
      *(uint4*)&Bs[r*48 + c*8] = v;
    }
    __syncthreads();
    short8 af[4], bfr[4];
    #pragma unroll
    for (int mt=0;mt<4;++mt)
      af[mt] = *(const short8*)&As[(m_off + mt*16 + lm)*48 + g*8];
    #pragma unroll
    for (int nt=0;nt<4;++nt)
      bfr[nt] = *(const short8*)&Bs[(n0 + nt*16 + lm)*48 + g*8];
    #pragma unroll
    for (int mt=0;mt<4;++mt)
      #pragma unroll
      for (int nt=0;nt<4;++nt)
        acc[mt][nt] = __builtin_amdgcn_mfma_f32_16x16x32_bf16(af[mt], bfr[nt], acc[mt][nt], 0, 0, 0);
  }

  float asv[4], adv[4];
  #pragma unroll
  for (int nt=0;nt<4;++nt){
    asv[nt] = a_s[n0 + nt*16 + lm];
    adv[nt] = a_d[n0 + nt*16 + lm];
  }
  const int head = (OUT==256) ? w : 0;
  #pragma unroll
  for (int mt=0;mt<4;++mt){
    #pragma unroll
    for (int reg=0;reg<4;++reg){
      int gr = m0 + m_off + mt*16 + g*4 + reg;
      bool valid = gr < N;
      float ps = 0.f, pd = 0.f;
      #pragma unroll
      for (int nt=0;nt<4;++nt){
        float v = acc[mt][nt][reg];
        if (valid){
          if constexpr (OUT==256){
            ((unsigned char*)outv)[(size_t)gr*256 + n0 + nt*16 + lm] = f2fp8(v);
          } else {
            ((bf16*)outv)[(size_t)gr*OUT + n0 + nt*16 + lm] = __float2bfloat16(v);
          }
        }
        ps = fmaf(v, asv[nt], ps);
        pd = fmaf(v, adv[nt], pd);
      }
      #pragma unroll
      for (int o=1;o<16;o<<=1){ ps += __shfl_xor(ps,o); pd += __shfl_xor(pd,o); }
      if (lm==0 && valid){
        als[gr*H + head] = ps;
        ald[gr*H + head] = pd;
      }
    }
  }
}

// ---------------- scan-free CSR build (by destination, + self-loops) ----------------
__global__ void count_kernel(const int* __restrict__ ei, int* __restrict__ deg,
        int E, int stride){
  int tid = blockIdx.x*blockDim.x+threadIdx.x;
  int d[4]; bool v[4];
  #pragma unroll
  for (int j=0;j<4;++j){
    int e = tid + j*stride;
    v[j] = e < E;
    d[j] = v[j] ? ei[E+e] : 0;
  }
  #pragma unroll
  for (int j=0;j<4;++j) if (v[j]) atomicAdd(&deg[d[j]], 1);
}
__global__ void assign_kernel(const int* __restrict__ deg, int* __restrict__ off,
        int* __restrict__ cursor, int* __restrict__ total, int N){
  int i = blockIdx.x*blockDim.x+threadIdx.x;
  if (i<N){
    int d = deg[i] + 1;                       // +1 self-loop
    int start = atomicAdd(total, d);          // unordered segments: fine
    off[i] = start; cursor[i] = start;
  }
}
__global__ void fill_kernel(const int* __restrict__ ei, int* __restrict__ cursor,
        int* __restrict__ csr_src, int E, int N, int stride){
  int tid = blockIdx.x*blockDim.x+threadIdx.x;
  const int ET = E + N;
  int s[4], d[4]; bool v[4];
  #pragma unroll
  for (int j=0;j<4;++j){
    int e = tid + j*stride;
    v[j] = e < ET;
    if (v[j]){
      s[j] = (e < E) ? ei[e]   : e-E;
      d[j] = (e < E) ? ei[E+e] : e-E;
    }
  }
  int p[4];
  #pragma unroll
  for (int j=0;j<4;++j) if (v[j]) p[j] = atomicAdd(&cursor[d[j]], 1);
  #pragma unroll
  for (int j=0;j<4;++j) if (v[j]) csr_src[p[j]] = s[j];
}

// ------- single-pass scatter-softmax + aggregate, H=4, fp8 h -------
// 2 nodes/block (128 thr, 2 independent waves, per-wave LDS slab).
// Per wave: lane = parity r (lane>>4, 4 edges) x feature-16 f (lane&15);
// uint4 = 16 fp8 => 4 rows/wave-instr, 2 loads in flight (step 8), scalar fma.
template<bool ELU>
__global__ __launch_bounds__(128) void aggregate4_kernel(const unsigned char* __restrict__ h8,
        const float* __restrict__ als, const float* __restrict__ ald,
        const int* __restrict__ off, const int* __restrict__ deg,
        const int* __restrict__ csr_src,
        const float* __restrict__ bias, bf16* __restrict__ out, int N){
  __shared__ int   s_src[2][64];
  __shared__ float s_w[2][64][4];
  const int wv = threadIdx.x>>6, lane = threadIdx.x&63;
  const int n = blockIdx.x*2 + wv;
  if (n >= N) return;
  const int r = lane>>4;            // edge parity (0..3)
  const int f = lane&15;            // features f*16..f*16+15
  const int head = f>>2;
  const int p0 = off[n], cnt = deg[n]+1;
  const float4 aldn4 = *(const float4*)(ald + n*4);
  float ssum = 0.f;
  float acc[16] = {};
  for (int c=0; c<cnt; c+=64){
    int e = c + lane;
    int src = n; float4 w4 = make_float4(0.f,0.f,0.f,0.f);
    if (e < cnt){
      src = csr_src[p0+e];
      float4 av = *(const float4*)(als + src*4);
      w4.x = __expf(leaky(av.x + aldn4.x));
      w4.y = __expf(leaky(av.y + aldn4.y));
      w4.z = __expf(leaky(av.z + aldn4.z));
      w4.w = __expf(leaky(av.w + aldn4.w));
    }
    s_src[wv][lane] = src;             // pad: src=n (valid addr), w=0
    *(float4*)&s_w[wv][lane][0] = w4;
    int ce = min(64, cnt - c);
    int cp = (ce+7)&~7;                // step 8: 2 uint4 loads in flight
    for (int i=0;i<cp;i+=8){
      int src0 = s_src[wv][i+r], src1 = s_src[wv][i+4+r];
      float w0 = s_w[wv][i+r][head], w1 = s_w[wv][i+4+r][head];
      uint4 h0 = *(const uint4*)(h8 + (size_t)src0*256 + f*16);
      uint4 h1 = *(const uint4*)(h8 + (size_t)src1*256 + f*16);
      ssum += w0 + w1;
      acc_fp8x4(acc+0,  h0.x, w0); acc_fp8x4(acc+4,  h0.y, w0);
      acc_fp8x4(acc+8,  h0.z, w0); acc_fp8x4(acc+12, h0.w, w0);
      acc_fp8x4(acc+0,  h1.x, w1); acc_fp8x4(acc+4,  h1.y, w1);
      acc_fp8x4(acc+8,  h1.z, w1); acc_fp8x4(acc+12, h1.w, w1);
    }
  }
  #pragma unroll
  for (int j=0;j<16;++j){
    acc[j] += __shfl_xor(acc[j], 16);
    acc[j] += __shfl_xor(acc[j], 32);
  }
  ssum += __shfl_xor(ssum, 16);
  ssum += __shfl_xor(ssum, 32);
  if (r==0){
    float inv = 1.f/(ssum + 1e-16f);
    #pragma unroll
    for (int half=0; half<2; ++half){
      float4 b0 = *(const float4*)(bias + f*16 + half*8);
      float4 b1 = *(const float4*)(bias + f*16 + half*8 + 4);
      float rv[8];
      rv[0]=acc[half*8+0]*inv+b0.x; rv[1]=acc[half*8+1]*inv+b0.y;
      rv[2]=acc[half*8+2]*inv+b0.z; rv[3]=acc[half*8+3]*inv+b0.w;
      rv[4]=acc[half*8+4]*inv+b1.x; rv[5]=acc[half*8+5]*inv+b1.y;
      rv[6]=acc[half*8+6]*inv+b1.z; rv[7]=acc[half*8+7]*inv+b1.w;
      union{ bf16 b[8]; uint4 u; } pk;
      #pragma unroll
      for (int j=0;j<8;++j){
        float v = rv[j];
        if (ELU) v = (v>0.f)?v:expm1f(v);
        pk.b[j] = __float2bfloat16(v);
      }
      *(uint4*)(out + (size_t)n*256 + f*16 + half*8) = pk.u;
    }
  }
}

// ------- single-pass scatter-softmax + aggregate, H=1, bf16 h -------
// 2 nodes/block (128 thr, 2 independent waves, per-wave LDS slab).
__global__ __launch_bounds__(128) void aggregate1_kernel(const bf16* __restrict__ h,
        const float* __restrict__ als, const float* __restrict__ ald,
        const int* __restrict__ off, const int* __restrict__ deg,
        const int* __restrict__ csr_src,
        const float* __restrict__ bias, bf16* __restrict__ out, int N){
  __shared__ int   s_src[2][64];
  __shared__ float s_w[2][64];
  const int wv = threadIdx.x>>6, lane = threadIdx.x&63;
  const int n = blockIdx.x*2 + wv;
  if (n >= N) return;
  const int r = lane>>4;            // edge parity (0..3)
  const int f = lane&15;            // feature quad: features f*4..f*4+3
  const int p0 = off[n], cnt = deg[n]+1;
  const float aldn = ald[n];
  float ssum = 0.f;
  float acc[4] = {};
  for (int c=0; c<cnt; c+=64){
    int e = c + lane;
    int src = n; float wgt = 0.f;
    if (e < cnt){
      src = csr_src[p0+e];
      wgt = __expf(leaky(als[src] + aldn));
    }
    s_src[wv][lane] = src; s_w[wv][lane] = wgt;
    int ce = min(64, cnt - c);
    int cp = (ce+7)&~7;              // step 8: 2 uint2 loads in flight
    for (int i=0;i<cp;i+=8){
      int src0 = s_src[wv][i+r], src1 = s_src[wv][i+4+r];
      float w0 = s_w[wv][i+r],   w1 = s_w[wv][i+4+r];
      uint2 h0 = *(const uint2*)(h + (size_t)src0*64 + f*4);
      uint2 h1 = *(const uint2*)(h + (size_t)src1*64 + f*4);
      ssum += w0 + w1;
      acc[0]=fmaf(bflo(h0.x),w0,acc[0]); acc[1]=fmaf(bfhi(h0.x),w0,acc[1]);
      acc[2]=fmaf(bflo(h0.y),w0,acc[2]); acc[3]=fmaf(bfhi(h0.y),w0,acc[3]);
      acc[0]=fmaf(bflo(h1.x),w1,acc[0]); acc[1]=fmaf(bfhi(h1.x),w1,acc[1]);
      acc[2]=fmaf(bflo(h1.y),w1,acc[2]); acc[3]=fmaf(bfhi(h1.y),w1,acc[3]);
    }
  }
  #pragma unroll
  for (int j=0;j<4;++j){
    acc[j] += __shfl_xor(acc[j], 16);
    acc[j] += __shfl_xor(acc[j], 32);
  }
  ssum += __shfl_xor(ssum, 16);
  ssum += __shfl_xor(ssum, 32);
  if (r==0){
    float inv = 1.f/(ssum + 1e-16f);
    union{ bf16 b[4]; uint2 u; } pk;
    #pragma unroll
    for (int j=0;j<4;++j) pk.b[j] = __float2bfloat16(acc[j]*inv + bias[f*4+j]);
    *(uint2*)(out + (size_t)n*64 + f*4) = pk.u;
  }
}

// ---------------- chunked pooling (batch sorted) ----------------
__global__ __launch_bounds__(64) void pool_kernel(const bf16* __restrict__ h3,
        const int* __restrict__ batch, float* __restrict__ psum, float* __restrict__ pcnt,
        int N, int chunk){
  int n0 = blockIdx.x*chunk;
  if (n0 >= N) return;
  int n1 = min(N, n0+chunk);
  int t = threadIdx.x;
  int gcur = batch[n0];
  float acc = 0.f, cnt = 0.f;
  for (int n=n0; n<n1; ++n){
    int g = batch[n];
    if (g != gcur){
      atomicAdd(&psum[gcur*64+t], acc);
      if (t==0) atomicAdd(&pcnt[gcur], cnt);
      acc = 0.f; cnt = 0.f; gcur = g;
    }
    acc += bf2f(h3[(size_t)n*64+t]);
    cnt += 1.f;
  }
  atomicAdd(&psum[gcur*64+t], acc);
  if (t==0) atomicAdd(&pcnt[gcur], cnt);
}

__global__ __launch_bounds__(64) void head_kernel(const float* __restrict__ psum,
        const float* __restrict__ pcnt,
        const float* __restrict__ Wmu, const float* __restrict__ bmu,
        const float* __restrict__ Wlv, const float* __restrict__ blv,
        float* __restrict__ out){
  int g = blockIdx.x, t = threadIdx.x;
  __shared__ float p[64];
  float cnt = fmaxf(pcnt[g], 1.0f);
  p[t] = psum[g*64+t] / cnt;
  __syncthreads();
  float mu = bmu[t], lv = blv[t];
  for (int k=0;k<64;++k){
    float pk = p[k];
    mu = fmaf(pk, Wmu[(size_t)k*64+t], mu);
    lv = fmaf(pk, Wlv[(size_t)k*64+t], lv);
  }
  int i = g*64 + t;
  unsigned x0 = 0u, x1 = (unsigned)i;
  threefry2x32(0u, 42u, x0, x1);
  unsigned bits = x0 ^ x1;
  float f = __uint_as_float((bits>>9) | 0x3F800000u) - 1.0f;   // [0,1)
  const float lo = __uint_as_float(0xBF7FFFFFu);               // -(1-2^-24)
  float u = fmaxf(lo, f*2.0f + lo);
  float eps = 1.41421356f * erfinv_approx(u);
  float z = mu + eps * expf(0.5f*lv);
  out[i]        = mu;
  out[4096 + i] = lv;
  out[8192 + i] = z;
}

// ---------------- launch ----------------
extern "C" void kernel_launch(void* const* d_in, const int* in_sizes, int n_in,
                              void* d_out, int out_size, void* d_ws, size_t ws_size,
                              hipStream_t stream){
  const float* x    = (const float*)d_in[0];
  const int*   ei   = (const int*)d_in[1];
  const int*   batch= (const int*)d_in[2];
  const float* W1   = (const float*)d_in[3];
  const float* a1s  = (const float*)d_in[4];
  const float* a1d  = (const float*)d_in[5];
  const float* b1   = (const float*)d_in[6];
  const float* W2   = (const float*)d_in[7];
  const float* a2s  = (const float*)d_in[8];
  const float* a2d  = (const float*)d_in[9];
  const float* b2   = (const float*)d_in[10];
  const float* W3   = (const float*)d_in[11];
  const float* a3s  = (const float*)d_in[12];
  const float* a3d  = (const float*)d_in[13];
  const float* b3   = (const float*)d_in[14];
  const float* Wmu  = (const float*)d_in[15];
  const float* bmu  = (const float*)d_in[16];
  const float* Wlv  = (const float*)d_in[17];
  const float* blv  = (const float*)d_in[18];
  float* out = (float*)d_out;

  const int N = N_NODES, E = N_EDGES;
  const int ET = E + N;

  char* ws = (char*)d_ws;
  size_t o = 0;
  auto alloc = [&](size_t bytes)->void*{
    void* p = ws + o; o += (bytes + 255) & ~(size_t)255; return p;
  };
  bf16*  hA      = (bf16*) alloc((size_t)N*256*2);       // 25.6 MB (agg out / gemm in)
  unsigned char* hB8 = (unsigned char*)alloc((size_t)N*256); // 12.8 MB fp8 gather payload
  bf16*  h3      = (bf16*) alloc((size_t)N*64*2);        // 6.4 MB (layer3 gemm out)
  float* als     = (float*)alloc((size_t)N*4*4);
  float* ald     = (float*)alloc((size_t)N*4*4);
  int*   deg     = (int*)  alloc((size_t)(N+1)*4);       // deg[N] = total
  int*   total   = deg + N;
  int*   off     = (int*)  alloc((size_t)N*4);
  int*   cursor  = (int*)  alloc((size_t)N*4);
  int*   csr_src = (int*)  alloc((size_t)ET*4);
  short* Wt1     = (short*)alloc(256*256*2);
  short* Wt2     = (short*)alloc(256*256*2);
  short* Wt3     = (short*)alloc(64*256*2);
  float* psum    = (float*)alloc(64*64*4 + 64*4);        // psum + pcnt contiguous
  float* pcnt    = psum + 64*64;
  (void)ws_size; (void)n_in; (void)in_sizes; (void)out_size;

  const int TB = 256;

  // W transposes (bf16 [n][k]) — single launch
  wt_all_kernel<<<dim3(8,8,3), 256, 0, stream>>>(W1, W2, W3, Wt1, Wt2, Wt3);

  // scan-free CSR by destination (rebuilt every call; ws re-poisoned per launch)
  hipMemsetAsync(deg, 0, (size_t)(N+1)*4, stream);
  {
    int cthreads = (E + 3)/4;
    int cgrid = (cthreads + TB - 1)/TB;
    count_kernel<<<cgrid, TB, 0, stream>>>(ei, deg, E, cgrid*TB);
  }
  assign_kernel<<<(N+TB-1)/TB, TB, 0, stream>>>(deg, off, cursor, total, N);
  {
    int fthreads = (ET + 3)/4;
    int fgrid = (fthreads + TB - 1)/TB;
    fill_kernel<<<fgrid, TB, 0, stream>>>(ei, cursor, csr_src, E, N, fgrid*TB);
  }

  const int agrid = (N + 1)/2;

  // ---- layer 1: x(f32) @ W1, H=4, ELU ----
  gemm_mfma_kernel<256,false><<<(N+63)/64, 256, 0, stream>>>(x, Wt1, hB8, a1s, a1d, als, ald, N);
  aggregate4_kernel<true><<<agrid, 128, 0, stream>>>(hB8, als, ald, off, deg, csr_src, b1, hA, N);

  // ---- layer 2: hA(bf16) @ W2, H=4, ELU ----
  gemm_mfma_kernel<256,true><<<(N+63)/64, 256, 0, stream>>>(hA, Wt2, hB8, a2s, a2d, als, ald, N);
  aggregate4_kernel<true><<<agrid, 128, 0, stream>>>(hB8, als, ald, off, deg, csr_src, b2, hA, N);

  // ---- layer 3: hA(bf16) @ W3, H=1, no ELU ----
  gemm_mfma_kernel<64,true><<<(N+255)/256, 256, 0, stream>>>(hA, Wt3, h3, a3s, a3d, als, ald, N);
  aggregate1_kernel<<<agrid, 128, 0, stream>>>(h3, als, ald, off, deg, csr_src, b3, hA, N);

  // ---- pool + VAE head ----
  hipMemsetAsync(psum, 0, 64*64*4 + 64*4, stream);
  const int PBLK = 512;
  const int chunk = (N + PBLK - 1)/PBLK;
  pool_kernel<<<PBLK, 64, 0, stream>>>(hA, batch, psum, pcnt, N, chunk);
  head_kernel<<<64, 64, 0, stream>>>(psum, pcnt, Wmu, bmu, Wlv, blv, out);
}